// Round 1
// 20157.439 us; speedup vs baseline: 1.5234x; 1.5234x over previous
//
#include <hip/hip_runtime.h>
#include <hip/hip_cooperative_groups.h>

namespace cg = cooperative_groups;

#define B_  64
#define T_  128
#define E_  512
#define HH_ 256
#define HN_ 1024
#define D_  4
#define V_  10000
#define NR_ (T_*D_)   // 512 chained updates
#define NWG_ 256

// ---- dynamic LDS layout (float offsets). Rows padded +4 floats so the 4
// jj-rows hit disjoint banks (pad 1024->1028 etc.; 2-way aliasing is free). ----
#define WH_OFF   0            // Wh:  8 rows x 1028   (rows w*4+jj, +HN)
#define WU_OFF   8224         // Wup: 4 rows x 260    (rows w*4+jj)
#define WI_OFF   9264         // Wi:  8 rows x 516    (rows w*4+jj, +HN)
#define WHH_OFF  13392        // Whh: 32 rows x 260   (rows ch0+rr, +HH)
#define WIH_OFF  21712        // Wih: 32 rows x 516
#define LDS_FLOATS 38224      // 152896 B  -> 1 WG/CU (intentional)

// -------------------------------------------------------------------------
// Custom two-phase flag barrier. cg::grid_group::sync() serializes 256
// device-scope atomic RMWs through one counter line (~45us/round measured as
// the non-VALU residual). Here: each WG stores a monotone round number to its
// OWN padded line (parallel, no RMW); block 0's 256 threads poll one line
// each, then publish a generation; others poll the generation.
// Data visibility: plain state stores are drained by __syncthreads (s_barrier
// implies vmcnt(0)), then one lane's agent-release fence writes back the
// XCD's dirty L2 lines BEFORE the flag store (agent-scope, bypasses L2).
// Reader side: agent-acquire fence (L1/L2 invalidate) before any state read.
// Flag values increase monotonically 1..513 -> no reset between rounds.
// -------------------------------------------------------------------------
__device__ __forceinline__ void flag_barrier(int* __restrict__ flags,
                                             int* __restrict__ gen,
                                             int w, int tau, int target)
{
    __syncthreads();                       // all waves' stores drained to L2
    if (tau == 0) {
        __builtin_amdgcn_fence(__ATOMIC_RELEASE, "agent");   // wb dirty L2
        __hip_atomic_store(&flags[w * 16], target, __ATOMIC_RELAXED,
                           __HIP_MEMORY_SCOPE_AGENT);
    }
    if (w == 0) {
        if (tau < NWG_) {
            while (__hip_atomic_load(&flags[tau * 16], __ATOMIC_RELAXED,
                                     __HIP_MEMORY_SCOPE_AGENT) < target) {
                __builtin_amdgcn_s_sleep(1);
            }
        }
        __syncthreads();                   // all flags seen
        if (tau == 0)
            __hip_atomic_store(gen, target, __ATOMIC_RELAXED,
                               __HIP_MEMORY_SCOPE_AGENT);
    } else if (tau == 0) {
        while (__hip_atomic_load(gen, __ATOMIC_RELAXED,
                                 __HIP_MEMORY_SCOPE_AGENT) < target) {
            __builtin_amdgcn_s_sleep(1);
        }
    }
    if (tau == 0)
        __builtin_amdgcn_fence(__ATOMIC_ACQUIRE, "agent");   // inv L1+L2
    __syncthreads();                       // fence done before anyone reads
}

// -------------------------------------------------------------------------
// Persistent cooperative recurrence. 256 WGs x 256 thr, 513 rounds.
// All per-WG weights live in LDS (persist across sync -> immune to the
// per-round L1/L2 coherence flush). Per-round global loads = state only,
// explicitly pipelined 16 float4s deep for MLP at 1 wave/SIMD.
// -------------------------------------------------------------------------
__global__ __launch_bounds__(256, 1) void recur_kernel(
    const int*   __restrict__ xx,
    const float* __restrict__ embed,
    const float* __restrict__ Whh, const float* __restrict__ bhh,
    const float* __restrict__ Wih, const float* __restrict__ bih,
    const float* __restrict__ Wh,  const float* __restrict__ bh,
    const float* __restrict__ Wi,  const float* __restrict__ bi,
    const float* __restrict__ Wup, const float* __restrict__ bup,
    float* __restrict__ sH,   // [2][B_][HH_]
    float* __restrict__ sN,   // [2][B_][HN_]
    float* __restrict__ hOut, // [B_*T_][HN_]
    int*   __restrict__ flags,
    int*   __restrict__ gen)
{
    extern __shared__ float lds[];
    cg::grid_group grid = cg::this_grid();
    const int w   = blockIdx.x;
    const int tau = threadIdx.x;
    const int gid = w * 256 + tau;
    const int ch0 = (w & 15) * 16;

    // ---------------- stage per-WG weights into LDS (once) ----------------
    for (int idx = tau; idx < 2048; idx += 256) {          // Wh 8x1024
        int r = idx >> 8, kq = idx & 255;
        int grow = w*4 + (r & 3) + (r >> 2) * HN_;
        *(float4*)&lds[WH_OFF + r*1028 + kq*4] =
            *(const float4*)(Wh + (size_t)grow * HN_ + kq*4);
    }
    for (int idx = tau; idx < 256; idx += 256) {           // Wup 4x256
        int r = idx >> 6, kq = idx & 63;
        *(float4*)&lds[WU_OFF + r*260 + kq*4] =
            *(const float4*)(Wup + (size_t)(w*4 + r) * HH_ + kq*4);
    }
    for (int idx = tau; idx < 1024; idx += 256) {          // Wi 8x512
        int r = idx >> 7, kq = idx & 127;
        int grow = w*4 + (r & 3) + (r >> 2) * HN_;
        *(float4*)&lds[WI_OFF + r*516 + kq*4] =
            *(const float4*)(Wi + (size_t)grow * E_ + kq*4);
    }
    for (int idx = tau; idx < 2048; idx += 256) {          // Whh 32x256
        int r = idx >> 6, kq = idx & 63;
        int grow = ch0 + (r & 15) + (r >> 4) * HH_;
        *(float4*)&lds[WHH_OFF + r*260 + kq*4] =
            *(const float4*)(Whh + (size_t)grow * HH_ + kq*4);
    }
    for (int idx = tau; idx < 4096; idx += 256) {          // Wih 32x512
        int r = idx >> 7, kq = idx & 127;
        int grow = ch0 + (r & 15) + (r >> 4) * HH_;
        *(float4*)&lds[WIH_OFF + r*516 + kq*4] =
            *(const float4*)(Wih + (size_t)grow * E_ + kq*4);
    }

    // init states (ws is poisoned 0xAA): sH parity 0, sN parity 1
    if (gid < B_ * HH_) sH[gid] = 0.f;
    sN[B_ * HN_ + gid] = 0.f;
    // init barrier flags (covered by the cg grid.sync release below)
    if (tau == 0) flags[w * 16] = 0;
    if (w == 0 && tau == 0) *gen = 0;
    __syncthreads();
    grid.sync();   // single cg sync: makes inits + LDS staging inputs coherent

    // ---------------- per-thread constants ----------------
    // sN side: thread = (b, jj), output column j = w*4+jj (and j+HN_)
    const int b  = tau >> 2;
    const int jj = tau & 3;
    const int j  = w * 4 + jj;
    const float bh1 = bh[j],  bh2 = bh[j + HN_];
    const float bi1 = bi[j],  bi2 = bi[j + HN_];
    const float bupj = bup[j];
    const float* wr1 = lds + WH_OFF + jj * 1028;
    const float* wr2 = lds + WH_OFF + (4 + jj) * 1028;
    const float* yr1 = lds + WI_OFF + jj * 516;
    const float* yr2 = lds + WI_OFF + (4 + jj) * 516;
    const float* ur  = lds + WU_OFF + jj * 260;

    // sH side: lanes tau%4==3 (spread across all 4 waves). item=(bH, ch)
    const bool hduty = (tau & 3) == 3;
    const int lane = tau >> 2;                  // 0..63
    const int ch   = ch0 + (lane & 15);
    const int bH   = (w >> 4) * 4 + (lane >> 4);
    const float bhh1 = bhh[ch], bhh2 = bhh[ch + HH_];
    const float bih1 = bih[ch], bih2 = bih[ch + HH_];
    const float* q1 = lds + WHH_OFF + (ch & 15) * 260;
    const float* q2 = lds + WHH_OFF + (16 + (ch & 15)) * 260;
    const float* p1 = lds + WIH_OFF + (ch & 15) * 516;
    const float* p2 = lds + WIH_OFF + (16 + (ch & 15)) * 516;

    for (int r = 0; r <= NR_; ++r) {
        const int p = r & 1;
        const float* sNp = sN + p * (B_ * HN_);
        const float* sHp = sH + p * (B_ * HH_);
        float* sNn = sN + (1 - p) * (B_ * HN_);
        float* sHn = sH + (1 - p) * (B_ * HH_);

        // ---------------- sN chain: update s = r-1 ----------------
        if (r >= 1) {
            const int s = r - 1;
            const int t = s >> 2;
            const int i = s & 3;

            float acc1 = bh1, acc2 = bh2;
            const float4* sv = (const float4*)(sNp + b * HN_);
            for (int kc = 0; kc < 256; kc += 16) {
                float4 sreg[16];
                #pragma unroll
                for (int u = 0; u < 16; ++u) sreg[u] = sv[kc + u];
                #pragma unroll
                for (int u = 0; u < 16; ++u) {
                    float4 a  = sreg[u];
                    float4 x1 = *(const float4*)(wr1 + (kc + u) * 4);
                    float4 x2 = *(const float4*)(wr2 + (kc + u) * 4);
                    acc1 += a.x*x1.x + a.y*x1.y + a.z*x1.z + a.w*x1.w;
                    acc2 += a.x*x2.x + a.y*x2.y + a.z*x2.z + a.w*x2.w;
                }
            }
            if (i == 0) {   // + (xt @ Wi.T + bi)
                const int tok = xx[b * T_ + t];
                const float4* ev = (const float4*)(embed + (size_t)tok * E_);
                float e1 = bi1, e2 = bi2;
                for (int kc = 0; kc < 128; kc += 16) {
                    float4 sreg[16];
                    #pragma unroll
                    for (int u = 0; u < 16; ++u) sreg[u] = ev[kc + u];
                    #pragma unroll
                    for (int u = 0; u < 16; ++u) {
                        float4 a  = sreg[u];
                        float4 x1 = *(const float4*)(yr1 + (kc + u) * 4);
                        float4 x2 = *(const float4*)(yr2 + (kc + u) * 4);
                        e1 += a.x*x1.x + a.y*x1.y + a.z*x1.z + a.w*x1.w;
                        e2 += a.x*x2.x + a.y*x2.y + a.z*x2.z + a.w*x2.w;
                    }
                }
                acc1 += e1; acc2 += e2;
            }
            // z = sH_new @ Wup.T + bup  (sHp IS post-update-(s) sH)
            float zv = bupj;
            {
                const float4* hv = (const float4*)(sHp + b * HH_);
                for (int kc = 0; kc < 64; kc += 16) {
                    float4 sreg[16];
                    #pragma unroll
                    for (int u = 0; u < 16; ++u) sreg[u] = hv[kc + u];
                    #pragma unroll
                    for (int u = 0; u < 16; ++u) {
                        float4 a  = sreg[u];
                        float4 x1 = *(const float4*)(ur + (kc + u) * 4);
                        zv += a.x*x1.x + a.y*x1.y + a.z*x1.z + a.w*x1.w;
                    }
                }
            }
            const float g_h = acc1 * zv;
            const float g_t = acc2 * zv;
            const float sg  = 1.f / (1.f + expf(-g_t));
            const float ov  = sNp[b * HN_ + j];
            const float nv  = tanhf(g_h) * sg + ov * (1.f - sg);
            sNn[b * HN_ + j] = nv;
            if (i == D_ - 1) hOut[(size_t)(b * T_ + t) * HN_ + j] = nv;
        }

        // ---------------- sH chain: update r ----------------
        if (r < NR_ && hduty) {
            const int t = r >> 2;
            const int i = r & 3;
            float a1 = bhh1, a2 = bhh2;
            const float4* svh = (const float4*)(sHp + bH * HH_);
            for (int kc = 0; kc < 64; kc += 16) {
                float4 sreg[16];
                #pragma unroll
                for (int u = 0; u < 16; ++u) sreg[u] = svh[kc + u];
                #pragma unroll
                for (int u = 0; u < 16; ++u) {
                    float4 a  = sreg[u];
                    float4 x1 = *(const float4*)(q1 + (kc + u) * 4);
                    float4 x2 = *(const float4*)(q2 + (kc + u) * 4);
                    a1 += a.x*x1.x + a.y*x1.y + a.z*x1.z + a.w*x1.w;
                    a2 += a.x*x2.x + a.y*x2.y + a.z*x2.z + a.w*x2.w;
                }
            }
            if (i == 0) {   // + (xt @ Wih.T + bih)
                const int tok = xx[bH * T_ + t];
                const float4* ev = (const float4*)(embed + (size_t)tok * E_);
                for (int kc = 0; kc < 128; kc += 16) {
                    float4 sreg[16];
                    #pragma unroll
                    for (int u = 0; u < 16; ++u) sreg[u] = ev[kc + u];
                    #pragma unroll
                    for (int u = 0; u < 16; ++u) {
                        float4 a  = sreg[u];
                        float4 x1 = *(const float4*)(p1 + (kc + u) * 4);
                        float4 x2 = *(const float4*)(p2 + (kc + u) * 4);
                        a1 += a.x*x1.x + a.y*x1.y + a.z*x1.z + a.w*x1.w;
                        a2 += a.x*x2.x + a.y*x2.y + a.z*x2.z + a.w*x2.w;
                    }
                }
                a1 += bih1; a2 += bih2;
            }
            const float sg = 1.f / (1.f + expf(-a2));
            const float ov = sHp[bH * HH_ + ch];
            sHn[bH * HH_ + ch] = tanhf(a1) * sg + ov * (1.f - sg);
        }

        flag_barrier(flags, gen, w, tau, r + 1);
    }
}

// -------------------------------------------------------------------------
// Output projection: out[bt, v] = h[bt, :] . Wout[v, :] + bout[v]
// M=8192, N=10000, K=1024. 64x64 tile, 256 threads, 4x4 acc/thread.
// -------------------------------------------------------------------------
__global__ __launch_bounds__(256) void out_gemm(
    const float* __restrict__ hb, const float* __restrict__ Wout,
    const float* __restrict__ bout, float* __restrict__ op)
{
    __shared__ float Ht[32][64];  // [k][m]
    __shared__ float Wt[32][64];  // [k][n]
    const int tau = threadIdx.x;
    const int tx  = tau & 15;
    const int ty  = tau >> 4;
    const int m0  = blockIdx.x * 64;
    const int n0  = blockIdx.y * 64;
    float acc[4][4] = {{0.f}};

    for (int k0 = 0; k0 < HN_; k0 += 32) {
        #pragma unroll
        for (int l = 0; l < 2; ++l) {
            const int f   = tau + l * 256;   // 0..511
            const int row = f >> 3;          // 64 rows
            const int kq  = (f & 7) * 4;     // 8 float4 per row
            float4 hv = *(const float4*)(hb + (size_t)(m0 + row) * HN_ + k0 + kq);
            Ht[kq + 0][row] = hv.x; Ht[kq + 1][row] = hv.y;
            Ht[kq + 2][row] = hv.z; Ht[kq + 3][row] = hv.w;
            const int vr = n0 + row;
            float4 wv = (vr < V_) ? *(const float4*)(Wout + (size_t)vr * HN_ + k0 + kq)
                                  : make_float4(0.f, 0.f, 0.f, 0.f);
            Wt[kq + 0][row] = wv.x; Wt[kq + 1][row] = wv.y;
            Wt[kq + 2][row] = wv.z; Wt[kq + 3][row] = wv.w;
        }
        __syncthreads();
        #pragma unroll
        for (int kk = 0; kk < 32; ++kk) {
            float4 av = *(const float4*)(&Ht[kk][ty * 4]);
            float4 bv = *(const float4*)(&Wt[kk][tx * 4]);
            acc[0][0] += av.x * bv.x; acc[0][1] += av.x * bv.y;
            acc[0][2] += av.x * bv.z; acc[0][3] += av.x * bv.w;
            acc[1][0] += av.y * bv.x; acc[1][1] += av.y * bv.y;
            acc[1][2] += av.y * bv.z; acc[1][3] += av.y * bv.w;
            acc[2][0] += av.z * bv.x; acc[2][1] += av.z * bv.y;
            acc[2][2] += av.z * bv.z; acc[2][3] += av.z * bv.w;
            acc[3][0] += av.w * bv.x; acc[3][1] += av.w * bv.y;
            acc[3][2] += av.w * bv.z; acc[3][3] += av.w * bv.w;
        }
        __syncthreads();
    }

    #pragma unroll
    for (int ii = 0; ii < 4; ++ii) {
        const int m = m0 + ty * 4 + ii;
        #pragma unroll
        for (int jq = 0; jq < 4; ++jq) {
            const int v = n0 + tx * 4 + jq;
            if (v < V_) op[(size_t)m * V_ + v] = acc[ii][jq] + bout[v];
        }
    }
}

extern "C" void kernel_launch(void* const* d_in, const int* in_sizes, int n_in,
                              void* d_out, int out_size, void* d_ws, size_t ws_size,
                              hipStream_t stream) {
    const int*   xx    = (const int*)  d_in[0];
    const float* embed = (const float*)d_in[1];
    const float* Whh   = (const float*)d_in[2];
    const float* bhh   = (const float*)d_in[3];
    const float* Wih   = (const float*)d_in[4];
    const float* bih   = (const float*)d_in[5];
    const float* Wh    = (const float*)d_in[6];
    const float* bh    = (const float*)d_in[7];
    const float* Wi    = (const float*)d_in[8];
    const float* bi    = (const float*)d_in[9];
    const float* Wup   = (const float*)d_in[10];
    const float* bup   = (const float*)d_in[11];
    const float* Wout  = (const float*)d_in[12];
    const float* bout  = (const float*)d_in[13];

    float* ws   = (float*)d_ws;
    float* hbuf = ws;                                   // 8192*1024 floats
    float* sHb  = hbuf + (size_t)B_ * T_ * HN_;         // 2*64*256
    float* sNb  = sHb + 2 * B_ * HH_;                   // 2*64*1024
    int*   flg  = (int*)(sNb + 2 * B_ * HN_);           // 256 padded lines
    int*   gen  = flg + NWG_ * 16;                      // own line

    void* args[] = { (void*)&xx, (void*)&embed, (void*)&Whh, (void*)&bhh,
                     (void*)&Wih, (void*)&bih, (void*)&Wh, (void*)&bh,
                     (void*)&Wi, (void*)&bi, (void*)&Wup, (void*)&bup,
                     (void*)&sHb, (void*)&sNb, (void*)&hbuf,
                     (void*)&flg, (void*)&gen };
    hipLaunchCooperativeKernel(reinterpret_cast<void*>(recur_kernel),
                               dim3(256), dim3(256), args,
                               (size_t)(LDS_FLOATS * 4), stream);

    out_gemm<<<dim3(T_ * B_ / 64, (V_ + 63) / 64), 256, 0, stream>>>(
        hbuf, Wout, bout, (float*)d_out);
}

// Round 2
// 15262.904 us; speedup vs baseline: 2.0120x; 1.3207x over previous
//
#include <hip/hip_runtime.h>
#include <hip/hip_cooperative_groups.h>

namespace cg = cooperative_groups;

typedef float v2f __attribute__((ext_vector_type(2)));

#define B_  64
#define T_  128
#define E_  512
#define HH_ 256
#define HN_ 1024
#define D_  4
#define V_  10000
#define NR_ (T_*D_)   // 512 chained updates
#define NWG_ 256

// ---- dynamic LDS layout (float offsets). Rows padded +8 floats (stride ≡ 8
// mod 32 banks) so the (jj,kk) read pattern 8*jj+4*kk mod 32 is exactly 2-way
// bank-aliased (free), with 4-lane broadcast over b. K-interleaved access:
// thread kk reads float4s kk, kk+4, kk+8, ... of its row. ----
#define WH_STR   1032
#define WI_STR   520
#define WS_STR   264
#define WH_OFF   0            // Wh:  8 rows x 1032  (rows w*4+jj, +HN)
#define WU_OFF   8256         // Wup: 4 rows x 264   (rows w*4+jj)
#define WI_OFF   9312         // Wi:  8 rows x 520   (rows w*4+jj, +HN)
#define WHH_OFF  13472        // Whh: 32 rows x 264  (rows ch0+rr, +HH)
#define WIH_OFF  21920        // Wih: 32 rows x 520
#define LDS_FLOATS 38560      // 154240 B -> 1 WG/CU (16 waves = 4/SIMD)

// -------------------------------------------------------------------------
// Two-phase flag barrier (R1: replaced cg::sync's serialized RMW funnel;
// measured -21us/round). Each WG stores a monotone round number to its own
// padded line; block 0's first 256 threads poll one line each, publish a
// generation; others poll the generation. Release fence (L2 writeback)
// before flag store; acquire fence (L1/L2 inv) before next round's reads.
// -------------------------------------------------------------------------
__device__ __forceinline__ void flag_barrier(int* __restrict__ flags,
                                             int* __restrict__ gen,
                                             int w, int tau, int target)
{
    __syncthreads();                       // all waves' stores drained
    if (tau == 0) {
        __builtin_amdgcn_fence(__ATOMIC_RELEASE, "agent");   // wb dirty L2
        __hip_atomic_store(&flags[w * 16], target, __ATOMIC_RELAXED,
                           __HIP_MEMORY_SCOPE_AGENT);
    }
    if (w == 0) {
        if (tau < NWG_) {
            while (__hip_atomic_load(&flags[tau * 16], __ATOMIC_RELAXED,
                                     __HIP_MEMORY_SCOPE_AGENT) < target) {
                __builtin_amdgcn_s_sleep(1);
            }
        }
        __syncthreads();                   // all flags seen
        if (tau == 0)
            __hip_atomic_store(gen, target, __ATOMIC_RELAXED,
                               __HIP_MEMORY_SCOPE_AGENT);
    } else if (tau == 0) {
        while (__hip_atomic_load(gen, __ATOMIC_RELAXED,
                                 __HIP_MEMORY_SCOPE_AGENT) < target) {
            __builtin_amdgcn_s_sleep(1);
        }
    }
    if (tau == 0)
        __builtin_amdgcn_fence(__ATOMIC_ACQUIRE, "agent");   // inv L1+L2
    __syncthreads();                       // fence done before anyone reads
}

// -------------------------------------------------------------------------
// Persistent cooperative recurrence. 256 WGs x 1024 thr (4 waves/SIMD for
// latency hiding — R1 was 1 wave/SIMD and latency-bound), 513 rounds.
// Work split: thread = (b, jj, kk); kk = K-dim quarter, reduced via
// __shfl_xor(1|2). sH chain on lanes tau&3==3 with its own 4-way K split
// (kkh = (tau>>2)&3, reduced via __shfl_xor(4|8)).
// -------------------------------------------------------------------------
__global__ __launch_bounds__(1024, 1) void recur_kernel(
    const int*   __restrict__ xx,
    const float* __restrict__ embed,
    const float* __restrict__ Whh, const float* __restrict__ bhh,
    const float* __restrict__ Wih, const float* __restrict__ bih,
    const float* __restrict__ Wh,  const float* __restrict__ bh,
    const float* __restrict__ Wi,  const float* __restrict__ bi,
    const float* __restrict__ Wup, const float* __restrict__ bup,
    float* __restrict__ sH,   // [2][B_][HH_]
    float* __restrict__ sN,   // [2][B_][HN_]
    float* __restrict__ hOut, // [B_*T_][HN_]
    int*   __restrict__ flags,
    int*   __restrict__ gen)
{
    extern __shared__ float lds[];
    cg::grid_group grid = cg::this_grid();
    const int w   = blockIdx.x;
    const int tau = threadIdx.x;
    const int gid = w * 1024 + tau;
    const int ch0 = (w & 15) * 16;

    // ---------------- stage per-WG weights into LDS (once) ----------------
    for (int idx = tau; idx < 2048; idx += 1024) {         // Wh 8x1024
        int r = idx >> 8, kq = idx & 255;
        int grow = w*4 + (r & 3) + (r >> 2) * HN_;
        *(float4*)&lds[WH_OFF + r*WH_STR + kq*4] =
            *(const float4*)(Wh + (size_t)grow * HN_ + kq*4);
    }
    if (tau < 256) {                                       // Wup 4x256
        int r = tau >> 6, kq = tau & 63;
        *(float4*)&lds[WU_OFF + r*WS_STR + kq*4] =
            *(const float4*)(Wup + (size_t)(w*4 + r) * HH_ + kq*4);
    }
    if (tau < 1024) {                                      // Wi 8x512
        int r = tau >> 7, kq = tau & 127;
        int grow = w*4 + (r & 3) + (r >> 2) * HN_;
        *(float4*)&lds[WI_OFF + r*WI_STR + kq*4] =
            *(const float4*)(Wi + (size_t)grow * E_ + kq*4);
    }
    for (int idx = tau; idx < 2048; idx += 1024) {         // Whh 32x256
        int r = idx >> 6, kq = idx & 63;
        int grow = ch0 + (r & 15) + (r >> 4) * HH_;
        *(float4*)&lds[WHH_OFF + r*WS_STR + kq*4] =
            *(const float4*)(Whh + (size_t)grow * HH_ + kq*4);
    }
    for (int idx = tau; idx < 4096; idx += 1024) {         // Wih 32x512
        int r = idx >> 7, kq = idx & 127;
        int grow = ch0 + (r & 15) + (r >> 4) * HH_;
        *(float4*)&lds[WIH_OFF + r*WI_STR + kq*4] =
            *(const float4*)(Wih + (size_t)grow * E_ + kq*4);
    }

    // init states (ws is poisoned 0xAA): sH parity 0, sN parity 1
    if (gid < B_ * HH_) sH[gid] = 0.f;
    if (gid < B_ * HN_) sN[B_ * HN_ + gid] = 0.f;
    if (tau == 0) flags[w * 16] = 0;
    if (w == 0 && tau == 0) *gen = 0;
    __syncthreads();
    grid.sync();   // single cg sync: inits + staging inputs coherent

    // ---------------- per-thread constants ----------------
    // sN side: thread = (b, jj, kk); output column j = w*4+jj (and j+HN_)
    const int kk = tau & 3;
    const int jj = (tau >> 2) & 3;
    const int b  = tau >> 4;
    const int j  = w * 4 + jj;
    const float bh1 = bh[j],  bh2 = bh[j + HN_];
    const float bi1 = bi[j],  bi2 = bi[j + HN_];
    const float bupj = bup[j];
    const float* wr1 = lds + WH_OFF + jj * WH_STR + kk * 4;
    const float* wr2 = lds + WH_OFF + (4 + jj) * WH_STR + kk * 4;
    const float* yr1 = lds + WI_OFF + jj * WI_STR + kk * 4;
    const float* yr2 = lds + WI_OFF + (4 + jj) * WI_STR + kk * 4;
    const float* ur  = lds + WU_OFF + jj * WS_STR + kk * 4;

    // sH side: lanes tau&3==3. item = tau>>4? No: kkh=(tau>>2)&3, item=tau>>4
    const bool hduty = (tau & 3) == 3;
    const int kkh  = (tau >> 2) & 3;
    const int item = tau >> 4;                  // 0..63
    const int ch   = ch0 + (item & 15);
    const int bH   = (w >> 4) * 4 + (item >> 4);
    const float bhh1 = bhh[ch], bhh2 = bhh[ch + HH_];
    const float bih1 = bih[ch], bih2 = bih[ch + HH_];
    const float* q1 = lds + WHH_OFF + (ch & 15) * WS_STR + kkh * 4;
    const float* q2 = lds + WHH_OFF + (16 + (ch & 15)) * WS_STR + kkh * 4;
    const float* p1 = lds + WIH_OFF + (ch & 15) * WI_STR + kkh * 4;
    const float* p2 = lds + WIH_OFF + (16 + (ch & 15)) * WI_STR + kkh * 4;

    for (int r = 0; r <= NR_; ++r) {
        const int p = r & 1;
        const float* sNp = sN + p * (B_ * HN_);
        const float* sHp = sH + p * (B_ * HH_);
        float* sNn = sN + (1 - p) * (B_ * HN_);
        float* sHn = sH + (1 - p) * (B_ * HH_);

        // ---------------- sN chain: update s = r-1 ----------------
        if (r >= 1) {
            const int s = r - 1;
            const int t = s >> 2;
            const int i = s & 3;

            v2f acc1 = {0.f, 0.f}, acc2 = {0.f, 0.f};
            const float4* sv = (const float4*)(sNp + b * HN_);
            for (int kc = 0; kc < 64; kc += 8) {
                float4 sreg[8];
                #pragma unroll
                for (int u = 0; u < 8; ++u) sreg[u] = sv[kk + 4*(kc + u)];
                #pragma unroll
                for (int u = 0; u < 8; ++u) {
                    float4 a  = sreg[u];
                    float4 x1 = *(const float4*)(wr1 + (kc + u) * 16);
                    float4 x2 = *(const float4*)(wr2 + (kc + u) * 16);
                    v2f a0 = {a.x, a.y},   a1v = {a.z, a.w};
                    v2f w10 = {x1.x, x1.y}, w11 = {x1.z, x1.w};
                    v2f w20 = {x2.x, x2.y}, w21 = {x2.z, x2.w};
                    acc1 += a0 * w10;  acc1 += a1v * w11;
                    acc2 += a0 * w20;  acc2 += a1v * w21;
                }
            }
            if (i == 0) {   // + xt @ Wi.T  (biases added after reduce)
                const int tok = xx[b * T_ + t];
                const float4* ev = (const float4*)(embed + (size_t)tok * E_);
                for (int kc = 0; kc < 32; kc += 8) {
                    float4 sreg[8];
                    #pragma unroll
                    for (int u = 0; u < 8; ++u) sreg[u] = ev[kk + 4*(kc + u)];
                    #pragma unroll
                    for (int u = 0; u < 8; ++u) {
                        float4 a  = sreg[u];
                        float4 x1 = *(const float4*)(yr1 + (kc + u) * 16);
                        float4 x2 = *(const float4*)(yr2 + (kc + u) * 16);
                        v2f a0 = {a.x, a.y},   a1v = {a.z, a.w};
                        v2f w10 = {x1.x, x1.y}, w11 = {x1.z, x1.w};
                        v2f w20 = {x2.x, x2.y}, w21 = {x2.z, x2.w};
                        acc1 += a0 * w10;  acc1 += a1v * w11;
                        acc2 += a0 * w20;  acc2 += a1v * w21;
                    }
                }
            }
            // z = sH_new @ Wup.T (sHp IS post-update-(s) sH)
            v2f zacc = {0.f, 0.f};
            {
                const float4* hv = (const float4*)(sHp + b * HH_);
                float4 sreg[8];
                #pragma unroll
                for (int u = 0; u < 8; ++u) sreg[u] = hv[kk + 4*u];
                #pragma unroll
                for (int u = 0; u < 8; ++u) {
                    float4 a  = sreg[u];
                    float4 x1 = *(const float4*)(ur + u * 16);
                    v2f a0 = {a.x, a.y},   a1v = {a.z, a.w};
                    v2f w10 = {x1.x, x1.y}, w11 = {x1.z, x1.w};
                    zacc += a0 * w10;  zacc += a1v * w11;
                }
                #pragma unroll
                for (int u = 8; u < 16; ++u) sreg[u-8] = hv[kk + 4*u];
                #pragma unroll
                for (int u = 8; u < 16; ++u) {
                    float4 a  = sreg[u-8];
                    float4 x1 = *(const float4*)(ur + u * 16);
                    v2f a0 = {a.x, a.y},   a1v = {a.z, a.w};
                    v2f w10 = {x1.x, x1.y}, w11 = {x1.z, x1.w};
                    zacc += a0 * w10;  zacc += a1v * w11;
                }
            }
            // reduce over kk (tau bits 0-1)
            float A1 = acc1.x + acc1.y;
            float A2 = acc2.x + acc2.y;
            float Z  = zacc.x + zacc.y;
            A1 += __shfl_xor(A1, 1); A1 += __shfl_xor(A1, 2);
            A2 += __shfl_xor(A2, 1); A2 += __shfl_xor(A2, 2);
            Z  += __shfl_xor(Z, 1);  Z  += __shfl_xor(Z, 2);
            if (kk == 0) {
                float g1 = A1 + bh1, g2 = A2 + bh2;
                if (i == 0) { g1 += bi1; g2 += bi2; }
                const float zv  = Z + bupj;
                const float g_h = g1 * zv;
                const float g_t = g2 * zv;
                const float sg  = 1.f / (1.f + expf(-g_t));
                const float ov  = sNp[b * HN_ + j];
                const float nv  = tanhf(g_h) * sg + ov * (1.f - sg);
                sNn[b * HN_ + j] = nv;
                if (i == D_ - 1) hOut[(size_t)(b * T_ + t) * HN_ + j] = nv;
            }
        }

        // ---------------- sH chain: update r ----------------
        if (r < NR_ && hduty) {
            const int t = r >> 2;
            const int i = r & 3;
            v2f A = {0.f, 0.f}, Bv = {0.f, 0.f};
            const float4* svh = (const float4*)(sHp + bH * HH_);
            {
                float4 sreg[8];
                #pragma unroll
                for (int u = 0; u < 8; ++u) sreg[u] = svh[kkh + 4*u];
                #pragma unroll
                for (int u = 0; u < 8; ++u) {
                    float4 a  = sreg[u];
                    float4 x1 = *(const float4*)(q1 + u * 16);
                    float4 x2 = *(const float4*)(q2 + u * 16);
                    v2f a0 = {a.x, a.y},   a1v = {a.z, a.w};
                    v2f w10 = {x1.x, x1.y}, w11 = {x1.z, x1.w};
                    v2f w20 = {x2.x, x2.y}, w21 = {x2.z, x2.w};
                    A  += a0 * w10;  A  += a1v * w11;
                    Bv += a0 * w20;  Bv += a1v * w21;
                }
                #pragma unroll
                for (int u = 8; u < 16; ++u) sreg[u-8] = svh[kkh + 4*u];
                #pragma unroll
                for (int u = 8; u < 16; ++u) {
                    float4 a  = sreg[u-8];
                    float4 x1 = *(const float4*)(q1 + u * 16);
                    float4 x2 = *(const float4*)(q2 + u * 16);
                    v2f a0 = {a.x, a.y},   a1v = {a.z, a.w};
                    v2f w10 = {x1.x, x1.y}, w11 = {x1.z, x1.w};
                    v2f w20 = {x2.x, x2.y}, w21 = {x2.z, x2.w};
                    A  += a0 * w10;  A  += a1v * w11;
                    Bv += a0 * w20;  Bv += a1v * w21;
                }
            }
            if (i == 0) {   // + xt @ Wih.T
                const int tok = xx[bH * T_ + t];
                const float4* ev = (const float4*)(embed + (size_t)tok * E_);
                for (int kc = 0; kc < 32; kc += 8) {
                    float4 sreg[8];
                    #pragma unroll
                    for (int u = 0; u < 8; ++u) sreg[u] = ev[kkh + 4*(kc + u)];
                    #pragma unroll
                    for (int u = 0; u < 8; ++u) {
                        float4 a  = sreg[u];
                        float4 x1 = *(const float4*)(p1 + (kc + u) * 16);
                        float4 x2 = *(const float4*)(p2 + (kc + u) * 16);
                        v2f a0 = {a.x, a.y},   a1v = {a.z, a.w};
                        v2f w10 = {x1.x, x1.y}, w11 = {x1.z, x1.w};
                        v2f w20 = {x2.x, x2.y}, w21 = {x2.z, x2.w};
                        A  += a0 * w10;  A  += a1v * w11;
                        Bv += a0 * w20;  Bv += a1v * w21;
                    }
                }
            }
            // reduce over kkh (tau bits 2-3)
            float a1 = A.x + A.y;
            float a2 = Bv.x + Bv.y;
            a1 += __shfl_xor(a1, 4); a1 += __shfl_xor(a1, 8);
            a2 += __shfl_xor(a2, 4); a2 += __shfl_xor(a2, 8);
            if (kkh == 0) {
                a1 += bhh1; a2 += bhh2;
                if (i == 0) { a1 += bih1; a2 += bih2; }
                const float sg = 1.f / (1.f + expf(-a2));
                const float ov = sHp[bH * HH_ + ch];
                sHn[bH * HH_ + ch] = tanhf(a1) * sg + ov * (1.f - sg);
            }
        }

        flag_barrier(flags, gen, w, tau, r + 1);
    }
}

// -------------------------------------------------------------------------
// Output projection: out[bt, v] = h[bt, :] . Wout[v, :] + bout[v]
// M=8192, N=10000, K=1024. 64x64 tile, 256 threads, 4x4 acc/thread.
// -------------------------------------------------------------------------
__global__ __launch_bounds__(256) void out_gemm(
    const float* __restrict__ hb, const float* __restrict__ Wout,
    const float* __restrict__ bout, float* __restrict__ op)
{
    __shared__ float Ht[32][64];  // [k][m]
    __shared__ float Wt[32][64];  // [k][n]
    const int tau = threadIdx.x;
    const int tx  = tau & 15;
    const int ty  = tau >> 4;
    const int m0  = blockIdx.x * 64;
    const int n0  = blockIdx.y * 64;
    float acc[4][4] = {{0.f}};

    for (int k0 = 0; k0 < HN_; k0 += 32) {
        #pragma unroll
        for (int l = 0; l < 2; ++l) {
            const int f   = tau + l * 256;   // 0..511
            const int row = f >> 3;          // 64 rows
            const int kq  = (f & 7) * 4;     // 8 float4 per row
            float4 hv = *(const float4*)(hb + (size_t)(m0 + row) * HN_ + k0 + kq);
            Ht[kq + 0][row] = hv.x; Ht[kq + 1][row] = hv.y;
            Ht[kq + 2][row] = hv.z; Ht[kq + 3][row] = hv.w;
            const int vr = n0 + row;
            float4 wv = (vr < V_) ? *(const float4*)(Wout + (size_t)vr * HN_ + k0 + kq)
                                  : make_float4(0.f, 0.f, 0.f, 0.f);
            Wt[kq + 0][row] = wv.x; Wt[kq + 1][row] = wv.y;
            Wt[kq + 2][row] = wv.z; Wt[kq + 3][row] = wv.w;
        }
        __syncthreads();
        #pragma unroll
        for (int kk = 0; kk < 32; ++kk) {
            float4 av = *(const float4*)(&Ht[kk][ty * 4]);
            float4 bv = *(const float4*)(&Wt[kk][tx * 4]);
            acc[0][0] += av.x * bv.x; acc[0][1] += av.x * bv.y;
            acc[0][2] += av.x * bv.z; acc[0][3] += av.x * bv.w;
            acc[1][0] += av.y * bv.x; acc[1][1] += av.y * bv.y;
            acc[1][2] += av.y * bv.z; acc[1][3] += av.y * bv.w;
            acc[2][0] += av.z * bv.x; acc[2][1] += av.z * bv.y;
            acc[2][2] += av.z * bv.z; acc[2][3] += av.z * bv.w;
            acc[3][0] += av.w * bv.x; acc[3][1] += av.w * bv.y;
            acc[3][2] += av.w * bv.z; acc[3][3] += av.w * bv.w;
        }
        __syncthreads();
    }

    #pragma unroll
    for (int ii = 0; ii < 4; ++ii) {
        const int m = m0 + ty * 4 + ii;
        #pragma unroll
        for (int jq = 0; jq < 4; ++jq) {
            const int v = n0 + tx * 4 + jq;
            if (v < V_) op[(size_t)m * V_ + v] = acc[ii][jq] + bout[v];
        }
    }
}

extern "C" void kernel_launch(void* const* d_in, const int* in_sizes, int n_in,
                              void* d_out, int out_size, void* d_ws, size_t ws_size,
                              hipStream_t stream) {
    const int*   xx    = (const int*)  d_in[0];
    const float* embed = (const float*)d_in[1];
    const float* Whh   = (const float*)d_in[2];
    const float* bhh   = (const float*)d_in[3];
    const float* Wih   = (const float*)d_in[4];
    const float* bih   = (const float*)d_in[5];
    const float* Wh    = (const float*)d_in[6];
    const float* bh    = (const float*)d_in[7];
    const float* Wi    = (const float*)d_in[8];
    const float* bi    = (const float*)d_in[9];
    const float* Wup   = (const float*)d_in[10];
    const float* bup   = (const float*)d_in[11];
    const float* Wout  = (const float*)d_in[12];
    const float* bout  = (const float*)d_in[13];

    float* ws   = (float*)d_ws;
    float* hbuf = ws;                                   // 8192*1024 floats
    float* sHb  = hbuf + (size_t)B_ * T_ * HN_;         // 2*64*256
    float* sNb  = sHb + 2 * B_ * HH_;                   // 2*64*1024
    int*   flg  = (int*)(sNb + 2 * B_ * HN_);           // 256 padded lines
    int*   gen  = flg + NWG_ * 16;                      // own line

    void* args[] = { (void*)&xx, (void*)&embed, (void*)&Whh, (void*)&bhh,
                     (void*)&Wih, (void*)&bih, (void*)&Wh, (void*)&bh,
                     (void*)&Wi, (void*)&bi, (void*)&Wup, (void*)&bup,
                     (void*)&sHb, (void*)&sNb, (void*)&hbuf,
                     (void*)&flg, (void*)&gen };
    hipLaunchCooperativeKernel(reinterpret_cast<void*>(recur_kernel),
                               dim3(256), dim3(1024), args,
                               (size_t)(LDS_FLOATS * 4), stream);

    out_gemm<<<dim3(T_ * B_ / 64, (V_ + 63) / 64), 256, 0, stream>>>(
        hbuf, Wout, bout, (float*)d_out);
}

// Round 3
// 13288.832 us; speedup vs baseline: 2.3109x; 1.1486x over previous
//
#include <hip/hip_runtime.h>
#include <hip/hip_cooperative_groups.h>

namespace cg = cooperative_groups;

typedef float v2f __attribute__((ext_vector_type(2)));

#define B_  64
#define T_  128
#define E_  512
#define HH_ 256
#define HN_ 1024
#define D_  4
#define V_  10000
#define NR_ (T_*D_)   // 512 chained updates
#define NWG_ 256

// ---- dynamic LDS layout (float offsets). Row strides ≡ 8 (mod 32 banks):
// wave-wide reads at float4 index (u*16+kk) give start banks (8*jj+4*kk)%32 →
// exactly 8 lanes per 4-bank slot = 8-cycle floor, zero conflicts, 1KB
// distinct data per ds_read_b128 instruction. ----
#define WH_STR   1032
#define WI_STR   520
#define WS_STR   264
#define WH_OFF   0            // Wh:  8 rows x 1032  (rows w*4+jj, +HN)
#define WU_OFF   8256         // Wup: 4 rows x 264   (rows w*4+jj)
#define WI_OFF   9312         // Wi:  8 rows x 520   (rows w*4+jj, +HN)
#define WHH_OFF  13472        // Whh: 32 rows x 264  (rows ch0+rr, +HH)
#define WIH_OFF  21920        // Wih: 32 rows x 520
#define LDS_FLOATS 38560      // 154240 B -> 1 WG/CU (16 waves = 4/SIMD)

// ---- 16-lane-row sum via DPP (VALU pipe, NOT the shared LDS pipe) ----
// quad_perm(1,0,3,2)=0xB1 (xor1), quad_perm(2,3,0,1)=0x4E (xor2),
// row_ror:4=0x124, row_ror:8=0x128. After 4 steps all 16 lanes of each
// DPP row hold the full row sum.
__device__ __forceinline__ float row16_sum(float x) {
    int v = __builtin_bit_cast(int, x);
    x += __builtin_bit_cast(float, __builtin_amdgcn_update_dpp(0, v, 0xB1, 0xF, 0xF, true));
    v = __builtin_bit_cast(int, x);
    x += __builtin_bit_cast(float, __builtin_amdgcn_update_dpp(0, v, 0x4E, 0xF, 0xF, true));
    v = __builtin_bit_cast(int, x);
    x += __builtin_bit_cast(float, __builtin_amdgcn_update_dpp(0, v, 0x124, 0xF, 0xF, true));
    v = __builtin_bit_cast(int, x);
    x += __builtin_bit_cast(float, __builtin_amdgcn_update_dpp(0, v, 0x128, 0xF, 0xF, true));
    return x;
}

__device__ __forceinline__ float sel4(int s, float a, float b, float c, float d) {
    return s == 0 ? a : (s == 1 ? b : (s == 2 ? c : d));
}

// -------------------------------------------------------------------------
// Two-phase flag barrier (R1: replaced cg::sync's serialized RMW funnel).
// -------------------------------------------------------------------------
__device__ __forceinline__ void flag_barrier(int* __restrict__ flags,
                                             int* __restrict__ gen,
                                             int w, int tau, int target)
{
    __syncthreads();                       // all waves' stores drained
    if (tau == 0) {
        __builtin_amdgcn_fence(__ATOMIC_RELEASE, "agent");   // wb dirty L2
        __hip_atomic_store(&flags[w * 16], target, __ATOMIC_RELAXED,
                           __HIP_MEMORY_SCOPE_AGENT);
    }
    if (w == 0) {
        if (tau < NWG_) {
            while (__hip_atomic_load(&flags[tau * 16], __ATOMIC_RELAXED,
                                     __HIP_MEMORY_SCOPE_AGENT) < target) {
                __builtin_amdgcn_s_sleep(1);
            }
        }
        __syncthreads();                   // all flags seen
        if (tau == 0)
            __hip_atomic_store(gen, target, __ATOMIC_RELAXED,
                               __HIP_MEMORY_SCOPE_AGENT);
    } else if (tau == 0) {
        while (__hip_atomic_load(gen, __ATOMIC_RELAXED,
                                 __HIP_MEMORY_SCOPE_AGENT) < target) {
            __builtin_amdgcn_s_sleep(1);
        }
    }
    if (tau == 0)
        __builtin_amdgcn_fence(__ATOMIC_ACQUIRE, "agent");   // inv L1+L2
    __syncthreads();                       // fence done before anyone reads
}

// -------------------------------------------------------------------------
// Persistent cooperative recurrence. 256 WGs x 1024 thr, 513 rounds.
// R3: LDS-throughput restructure. Wave bq handles b-quad {bq*4..bq*4+3};
// lane = (jj = lane>>4, kk = lane&15). Every ds_read_b128 is wave-wide
// distinct (1KB/instr, conflict-free). K-reduce (16-way over kk) via DPP.
// -------------------------------------------------------------------------
__global__ __launch_bounds__(1024, 1) void recur_kernel(
    const int*   __restrict__ xx,
    const float* __restrict__ embed,
    const float* __restrict__ Whh, const float* __restrict__ bhh,
    const float* __restrict__ Wih, const float* __restrict__ bih,
    const float* __restrict__ Wh,  const float* __restrict__ bh,
    const float* __restrict__ Wi,  const float* __restrict__ bi,
    const float* __restrict__ Wup, const float* __restrict__ bup,
    float* __restrict__ sH,   // [2][B_][HH_]
    float* __restrict__ sN,   // [2][B_][HN_]
    float* __restrict__ hOut, // [B_*T_][HN_]
    int*   __restrict__ flags,
    int*   __restrict__ gen)
{
    extern __shared__ float lds[];
    cg::grid_group grid = cg::this_grid();
    const int w   = blockIdx.x;
    const int tau = threadIdx.x;
    const int gid = w * 1024 + tau;
    const int ch0 = (w & 15) * 16;

    // ---------------- stage per-WG weights into LDS (once) ----------------
    for (int idx = tau; idx < 2048; idx += 1024) {         // Wh 8x1024
        int r = idx >> 8, kq = idx & 255;
        int grow = w*4 + (r & 3) + (r >> 2) * HN_;
        *(float4*)&lds[WH_OFF + r*WH_STR + kq*4] =
            *(const float4*)(Wh + (size_t)grow * HN_ + kq*4);
    }
    if (tau < 256) {                                       // Wup 4x256
        int r = tau >> 6, kq = tau & 63;
        *(float4*)&lds[WU_OFF + r*WS_STR + kq*4] =
            *(const float4*)(Wup + (size_t)(w*4 + r) * HH_ + kq*4);
    }
    if (tau < 1024) {                                      // Wi 8x512
        int r = tau >> 7, kq = tau & 127;
        int grow = w*4 + (r & 3) + (r >> 2) * HN_;
        *(float4*)&lds[WI_OFF + r*WI_STR + kq*4] =
            *(const float4*)(Wi + (size_t)grow * E_ + kq*4);
    }
    for (int idx = tau; idx < 2048; idx += 1024) {         // Whh 32x256
        int r = idx >> 6, kq = idx & 63;
        int grow = ch0 + (r & 15) + (r >> 4) * HH_;
        *(float4*)&lds[WHH_OFF + r*WS_STR + kq*4] =
            *(const float4*)(Whh + (size_t)grow * HH_ + kq*4);
    }
    for (int idx = tau; idx < 4096; idx += 1024) {         // Wih 32x512
        int r = idx >> 7, kq = idx & 127;
        int grow = ch0 + (r & 15) + (r >> 4) * HH_;
        *(float4*)&lds[WIH_OFF + r*WI_STR + kq*4] =
            *(const float4*)(Wih + (size_t)grow * E_ + kq*4);
    }

    // init states (ws is poisoned 0xAA): sH parity 0, sN parity 1
    if (gid < B_ * HH_) sH[gid] = 0.f;
    if (gid < B_ * HN_) sN[B_ * HN_ + gid] = 0.f;
    if (tau == 0) flags[w * 16] = 0;
    if (w == 0 && tau == 0) *gen = 0;
    __syncthreads();
    grid.sync();   // single cg sync: inits + staging inputs coherent

    // ---------------- per-thread constants ----------------
    const int lane = tau & 63;
    const int bq   = tau >> 6;        // wave id = b-quad (b = bq*4+bb)
    const int kk   = lane & 15;       // K-split 16 (DPP-row dimension)
    const int jj   = lane >> 4;       // output col within WG's 4 / bH index

    // sN side
    const int j = w * 4 + jj;
    const float bh1 = bh[j],  bh2 = bh[j + HN_];
    const float bi1 = bi[j],  bi2 = bi[j + HN_];
    const float bupj = bup[j];
    const float* wrow1 = lds + WH_OFF + jj * WH_STR;        // Wh[j]
    const float* wrow2 = lds + WH_OFF + (4 + jj) * WH_STR;  // Wh[j+HN]
    const float* urow  = lds + WU_OFF + jj * WS_STR;        // Wup[j]
    const float* yrow1 = lds + WI_OFF + jj * WI_STR;        // Wi[j]
    const float* yrow2 = lds + WI_OFF + (4 + jj) * WI_STR;  // Wi[j+HN]

    // sH side: wave bq owns channel ch; lane row jj -> batch bH
    const int ch = ch0 + bq;
    const int bH = (w >> 4) * 4 + jj;
    const float bhh1 = bhh[ch], bhh2 = bhh[ch + HH_];
    const float bih1 = bih[ch], bih2 = bih[ch + HH_];
    const float* qrow1 = lds + WHH_OFF + bq * WS_STR;         // Whh[ch]
    const float* qrow2 = lds + WHH_OFF + (16 + bq) * WS_STR;  // Whh[ch+HH]
    const float* prow1 = lds + WIH_OFF + bq * WI_STR;         // Wih[ch]
    const float* prow2 = lds + WIH_OFF + (16 + bq) * WI_STR;  // Wih[ch+HH]

    for (int r = 0; r <= NR_; ++r) {
        const int p = r & 1;
        const float* sNp = sN + p * (B_ * HN_);
        const float* sHp = sH + p * (B_ * HH_);
        float* sNn = sN + (1 - p) * (B_ * HN_);
        float* sHn = sH + (1 - p) * (B_ * HH_);

        // ---------------- sN chain: update s = r-1 ----------------
        if (r >= 1) {
            const int s = r - 1;
            const int t = s >> 2;
            const int i = s & 3;

            const float* sb0 = sNp + (bq * 4 + 0) * HN_;
            const float* sb1 = sNp + (bq * 4 + 1) * HN_;
            const float* sb2 = sNp + (bq * 4 + 2) * HN_;
            const float* sb3 = sNp + (bq * 4 + 3) * HN_;

            v2f A1[4], A2[4], Z[4];
            #pragma unroll
            for (int bb = 0; bb < 4; ++bb) { A1[bb] = (v2f){0.f,0.f}; A2[bb] = (v2f){0.f,0.f}; Z[bb] = (v2f){0.f,0.f}; }

            #pragma unroll
            for (int u = 0; u < 16; ++u) {
                const int fi = (u * 16 + kk) * 4;
                float4 w1 = *(const float4*)(wrow1 + fi);
                float4 w2 = *(const float4*)(wrow2 + fi);
                float4 s0 = *(const float4*)(sb0 + fi);
                float4 s1 = *(const float4*)(sb1 + fi);
                float4 s2 = *(const float4*)(sb2 + fi);
                float4 s3 = *(const float4*)(sb3 + fi);
                v2f w1l = {w1.x, w1.y}, w1h = {w1.z, w1.w};
                v2f w2l = {w2.x, w2.y}, w2h = {w2.z, w2.w};
                v2f a;
                a = (v2f){s0.x, s0.y}; A1[0] += a * w1l; A2[0] += a * w2l;
                a = (v2f){s0.z, s0.w}; A1[0] += a * w1h; A2[0] += a * w2h;
                a = (v2f){s1.x, s1.y}; A1[1] += a * w1l; A2[1] += a * w2l;
                a = (v2f){s1.z, s1.w}; A1[1] += a * w1h; A2[1] += a * w2h;
                a = (v2f){s2.x, s2.y}; A1[2] += a * w1l; A2[2] += a * w2l;
                a = (v2f){s2.z, s2.w}; A1[2] += a * w1h; A2[2] += a * w2h;
                a = (v2f){s3.x, s3.y}; A1[3] += a * w1l; A2[3] += a * w2l;
                a = (v2f){s3.z, s3.w}; A1[3] += a * w1h; A2[3] += a * w2h;
            }

            if (i == 0) {   // + xt @ Wi.T (biases added post-reduce)
                const int t0 = xx[(bq * 4 + 0) * T_ + t];
                const int t1 = xx[(bq * 4 + 1) * T_ + t];
                const int t2 = xx[(bq * 4 + 2) * T_ + t];
                const int t3 = xx[(bq * 4 + 3) * T_ + t];
                const float* e0 = embed + (size_t)t0 * E_;
                const float* e1 = embed + (size_t)t1 * E_;
                const float* e2 = embed + (size_t)t2 * E_;
                const float* e3 = embed + (size_t)t3 * E_;
                #pragma unroll
                for (int u = 0; u < 8; ++u) {
                    const int fi = (u * 16 + kk) * 4;
                    float4 y1 = *(const float4*)(yrow1 + fi);
                    float4 y2 = *(const float4*)(yrow2 + fi);
                    float4 v0 = *(const float4*)(e0 + fi);
                    float4 v1 = *(const float4*)(e1 + fi);
                    float4 v2 = *(const float4*)(e2 + fi);
                    float4 v3 = *(const float4*)(e3 + fi);
                    v2f y1l = {y1.x, y1.y}, y1h = {y1.z, y1.w};
                    v2f y2l = {y2.x, y2.y}, y2h = {y2.z, y2.w};
                    v2f a;
                    a = (v2f){v0.x, v0.y}; A1[0] += a * y1l; A2[0] += a * y2l;
                    a = (v2f){v0.z, v0.w}; A1[0] += a * y1h; A2[0] += a * y2h;
                    a = (v2f){v1.x, v1.y}; A1[1] += a * y1l; A2[1] += a * y2l;
                    a = (v2f){v1.z, v1.w}; A1[1] += a * y1h; A2[1] += a * y2h;
                    a = (v2f){v2.x, v2.y}; A1[2] += a * y1l; A2[2] += a * y2l;
                    a = (v2f){v2.z, v2.w}; A1[2] += a * y1h; A2[2] += a * y2h;
                    a = (v2f){v3.x, v3.y}; A1[3] += a * y1l; A2[3] += a * y2l;
                    a = (v2f){v3.z, v3.w}; A1[3] += a * y1h; A2[3] += a * y2h;
                }
            }

            // z = sH_new @ Wup.T (sHp IS post-update-(s) sH)
            {
                const float* hb0 = sHp + (bq * 4 + 0) * HH_;
                const float* hb1 = sHp + (bq * 4 + 1) * HH_;
                const float* hb2 = sHp + (bq * 4 + 2) * HH_;
                const float* hb3 = sHp + (bq * 4 + 3) * HH_;
                #pragma unroll
                for (int u = 0; u < 4; ++u) {
                    const int fi = (u * 16 + kk) * 4;
                    float4 uw = *(const float4*)(urow + fi);
                    float4 h0 = *(const float4*)(hb0 + fi);
                    float4 h1 = *(const float4*)(hb1 + fi);
                    float4 h2 = *(const float4*)(hb2 + fi);
                    float4 h3 = *(const float4*)(hb3 + fi);
                    v2f ul = {uw.x, uw.y}, uh = {uw.z, uw.w};
                    v2f a;
                    a = (v2f){h0.x, h0.y}; Z[0] += a * ul;
                    a = (v2f){h0.z, h0.w}; Z[0] += a * uh;
                    a = (v2f){h1.x, h1.y}; Z[1] += a * ul;
                    a = (v2f){h1.z, h1.w}; Z[1] += a * uh;
                    a = (v2f){h2.x, h2.y}; Z[2] += a * ul;
                    a = (v2f){h2.z, h2.w}; Z[2] += a * uh;
                    a = (v2f){h3.x, h3.y}; Z[3] += a * ul;
                    a = (v2f){h3.z, h3.w}; Z[3] += a * uh;
                }
            }

            // K-reduce over kk (16 lanes within DPP row) — VALU pipe only
            float a1r0 = row16_sum(A1[0].x + A1[0].y);
            float a1r1 = row16_sum(A1[1].x + A1[1].y);
            float a1r2 = row16_sum(A1[2].x + A1[2].y);
            float a1r3 = row16_sum(A1[3].x + A1[3].y);
            float a2r0 = row16_sum(A2[0].x + A2[0].y);
            float a2r1 = row16_sum(A2[1].x + A2[1].y);
            float a2r2 = row16_sum(A2[2].x + A2[2].y);
            float a2r3 = row16_sum(A2[3].x + A2[3].y);
            float zr0  = row16_sum(Z[0].x + Z[0].y);
            float zr1  = row16_sum(Z[1].x + Z[1].y);
            float zr2  = row16_sum(Z[2].x + Z[2].y);
            float zr3  = row16_sum(Z[3].x + Z[3].y);

            const int bsel = bq * 4 + (kk & 3);
            const float ov = sNp[bsel * HN_ + j];   // issued early for all lanes

            if (kk < 4) {
                float g1 = sel4(kk, a1r0, a1r1, a1r2, a1r3) + bh1;
                float g2 = sel4(kk, a2r0, a2r1, a2r2, a2r3) + bh2;
                if (i == 0) { g1 += bi1; g2 += bi2; }
                const float zv  = sel4(kk, zr0, zr1, zr2, zr3) + bupj;
                const float g_h = g1 * zv;
                const float g_t = g2 * zv;
                const float sg  = 1.f / (1.f + expf(-g_t));
                const float nv  = tanhf(g_h) * sg + ov * (1.f - sg);
                sNn[bsel * HN_ + j] = nv;
                if (i == D_ - 1) hOut[(size_t)(bsel * T_ + t) * HN_ + j] = nv;
            }
        }

        // ---------------- sH chain: update r ----------------
        if (r < NR_) {
            const int t = r >> 2;
            const int i = r & 3;
            v2f a1v = {0.f, 0.f}, a2v = {0.f, 0.f};
            const float* shb = sHp + bH * HH_;
            #pragma unroll
            for (int uu = 0; uu < 4; ++uu) {
                const int fi = (((jj + uu) & 3) * 16 + kk) * 4;  // g-staggered: wave-wide distinct
                float4 q1 = *(const float4*)(qrow1 + fi);
                float4 q2 = *(const float4*)(qrow2 + fi);
                float4 sv = *(const float4*)(shb + fi);
                v2f q1l = {q1.x, q1.y}, q1h = {q1.z, q1.w};
                v2f q2l = {q2.x, q2.y}, q2h = {q2.z, q2.w};
                v2f a;
                a = (v2f){sv.x, sv.y}; a1v += a * q1l; a2v += a * q2l;
                a = (v2f){sv.z, sv.w}; a1v += a * q1h; a2v += a * q2h;
            }
            if (i == 0) {   // + xt @ Wih.T
                const int tok = xx[bH * T_ + t];
                const float* eb = embed + (size_t)tok * E_;
                #pragma unroll
                for (int uu = 0; uu < 4; ++uu) {
                    const int fi = (((jj + uu) & 3) * 16 + kk) * 4;
                    float4 p1a = *(const float4*)(prow1 + fi);
                    float4 p1b = *(const float4*)(prow1 + fi + 256);
                    float4 p2a = *(const float4*)(prow2 + fi);
                    float4 p2b = *(const float4*)(prow2 + fi + 256);
                    float4 ea  = *(const float4*)(eb + fi);
                    float4 eb2 = *(const float4*)(eb + fi + 256);
                    v2f a;
                    a = (v2f){ea.x, ea.y};  a1v += a * (v2f){p1a.x, p1a.y}; a2v += a * (v2f){p2a.x, p2a.y};
                    a = (v2f){ea.z, ea.w};  a1v += a * (v2f){p1a.z, p1a.w}; a2v += a * (v2f){p2a.z, p2a.w};
                    a = (v2f){eb2.x, eb2.y}; a1v += a * (v2f){p1b.x, p1b.y}; a2v += a * (v2f){p2b.x, p2b.y};
                    a = (v2f){eb2.z, eb2.w}; a1v += a * (v2f){p1b.z, p1b.w}; a2v += a * (v2f){p2b.z, p2b.w};
                }
            }
            float a1 = row16_sum(a1v.x + a1v.y);
            float a2 = row16_sum(a2v.x + a2v.y);
            const float ovh = sHp[bH * HH_ + ch];   // issued early
            if (kk == 0) {
                a1 += bhh1; a2 += bhh2;
                if (i == 0) { a1 += bih1; a2 += bih2; }
                const float sg = 1.f / (1.f + expf(-a2));
                sHn[bH * HH_ + ch] = tanhf(a1) * sg + ovh * (1.f - sg);
            }
        }

        flag_barrier(flags, gen, w, tau, r + 1);
    }
}

// -------------------------------------------------------------------------
// Output projection: out[bt, v] = h[bt, :] . Wout[v, :] + bout[v]
// M=8192, N=10000, K=1024. 64x64 tile, 256 threads, 4x4 acc/thread.
// -------------------------------------------------------------------------
__global__ __launch_bounds__(256) void out_gemm(
    const float* __restrict__ hb, const float* __restrict__ Wout,
    const float* __restrict__ bout, float* __restrict__ op)
{
    __shared__ float Ht[32][64];  // [k][m]
    __shared__ float Wt[32][64];  // [k][n]
    const int tau = threadIdx.x;
    const int tx  = tau & 15;
    const int ty  = tau >> 4;
    const int m0  = blockIdx.x * 64;
    const int n0  = blockIdx.y * 64;
    float acc[4][4] = {{0.f}};

    for (int k0 = 0; k0 < HN_; k0 += 32) {
        #pragma unroll
        for (int l = 0; l < 2; ++l) {
            const int f   = tau + l * 256;   // 0..511
            const int row = f >> 3;          // 64 rows
            const int kq  = (f & 7) * 4;     // 8 float4 per row
            float4 hv = *(const float4*)(hb + (size_t)(m0 + row) * HN_ + k0 + kq);
            Ht[kq + 0][row] = hv.x; Ht[kq + 1][row] = hv.y;
            Ht[kq + 2][row] = hv.z; Ht[kq + 3][row] = hv.w;
            const int vr = n0 + row;
            float4 wv = (vr < V_) ? *(const float4*)(Wout + (size_t)vr * HN_ + k0 + kq)
                                  : make_float4(0.f, 0.f, 0.f, 0.f);
            Wt[kq + 0][row] = wv.x; Wt[kq + 1][row] = wv.y;
            Wt[kq + 2][row] = wv.z; Wt[kq + 3][row] = wv.w;
        }
        __syncthreads();
        #pragma unroll
        for (int kq = 0; kq < 32; ++kq) {
            float4 av = *(const float4*)(&Ht[kq][ty * 4]);
            float4 bv = *(const float4*)(&Wt[kq][tx * 4]);
            acc[0][0] += av.x * bv.x; acc[0][1] += av.x * bv.y;
            acc[0][2] += av.x * bv.z; acc[0][3] += av.x * bv.w;
            acc[1][0] += av.y * bv.x; acc[1][1] += av.y * bv.y;
            acc[1][2] += av.y * bv.z; acc[1][3] += av.y * bv.w;
            acc[2][0] += av.z * bv.x; acc[2][1] += av.z * bv.y;
            acc[2][2] += av.z * bv.z; acc[2][3] += av.z * bv.w;
            acc[3][0] += av.w * bv.x; acc[3][1] += av.w * bv.y;
            acc[3][2] += av.w * bv.z; acc[3][3] += av.w * bv.w;
        }
        __syncthreads();
    }

    #pragma unroll
    for (int ii = 0; ii < 4; ++ii) {
        const int m = m0 + ty * 4 + ii;
        #pragma unroll
        for (int jq = 0; jq < 4; ++jq) {
            const int v = n0 + tx * 4 + jq;
            if (v < V_) op[(size_t)m * V_ + v] = acc[ii][jq] + bout[v];
        }
    }
}

extern "C" void kernel_launch(void* const* d_in, const int* in_sizes, int n_in,
                              void* d_out, int out_size, void* d_ws, size_t ws_size,
                              hipStream_t stream) {
    const int*   xx    = (const int*)  d_in[0];
    const float* embed = (const float*)d_in[1];
    const float* Whh   = (const float*)d_in[2];
    const float* bhh   = (const float*)d_in[3];
    const float* Wih   = (const float*)d_in[4];
    const float* bih   = (const float*)d_in[5];
    const float* Wh    = (const float*)d_in[6];
    const float* bh    = (const float*)d_in[7];
    const float* Wi    = (const float*)d_in[8];
    const float* bi    = (const float*)d_in[9];
    const float* Wup   = (const float*)d_in[10];
    const float* bup   = (const float*)d_in[11];
    const float* Wout  = (const float*)d_in[12];
    const float* bout  = (const float*)d_in[13];

    float* ws   = (float*)d_ws;
    float* hbuf = ws;                                   // 8192*1024 floats
    float* sHb  = hbuf + (size_t)B_ * T_ * HN_;         // 2*64*256
    float* sNb  = sHb + 2 * B_ * HH_;                   // 2*64*1024
    int*   flg  = (int*)(sNb + 2 * B_ * HN_);           // 256 padded lines
    int*   gen  = flg + NWG_ * 16;                      // own line

    void* args[] = { (void*)&xx, (void*)&embed, (void*)&Whh, (void*)&bhh,
                     (void*)&Wih, (void*)&bih, (void*)&Wh, (void*)&bh,
                     (void*)&Wi, (void*)&bi, (void*)&Wup, (void*)&bup,
                     (void*)&sHb, (void*)&sNb, (void*)&hbuf,
                     (void*)&flg, (void*)&gen };
    hipLaunchCooperativeKernel(reinterpret_cast<void*>(recur_kernel),
                               dim3(256), dim3(1024), args,
                               (size_t)(LDS_FLOATS * 4), stream);

    out_gemm<<<dim3(T_ * B_ / 64, (V_ + 63) / 64), 256, 0, stream>>>(
        hbuf, Wout, bout, (float*)d_out);
}